// Round 1
// baseline (357.954 us; speedup 1.0000x reference)
//
#include <hip/hip_runtime.h>
#include <hip/hip_bf16.h>

// Problem constants (from reference): B,T,L,R,E,F
#define B_ 8
#define T_ 16
#define L_ 128
#define R_ 1024
#define E_ 5
#define F_ 512

typedef short short8 __attribute__((ext_vector_type(8)));
typedef float floatx4 __attribute__((ext_vector_type(4)));

// fp32 -> bf16 bits, round-half-up (differs from RNE only on exact .5 ties: prob 2^-16, negligible bias)
__device__ __forceinline__ unsigned short f2bf(float f) {
  unsigned u = __float_as_uint(f);
  return (unsigned short)((u + 0x8000u) >> 16);
}

__device__ __forceinline__ short8 pack8(floatx4 lo, floatx4 hi) {
  short8 v;
  v[0] = (short)f2bf(lo[0]); v[1] = (short)f2bf(lo[1]);
  v[2] = (short)f2bf(lo[2]); v[3] = (short)f2bf(lo[3]);
  v[4] = (short)f2bf(hi[0]); v[5] = (short)f2bf(hi[1]);
  v[6] = (short)f2bf(hi[2]); v[7] = (short)f2bf(hi[3]);
  return v;
}

// ---------------------------------------------------------------------------
// Kernel 1: rot = QR(pre_rot).Q  (LAPACK Householder convention, matches
// numpy/jax sgeqrf+sorgqr incl. R-diagonal signs), then
// new_lig[b,t,l,:] = rot[b,t] @ lig_coord[b,l] + trans[b,t].
// Grid: B*T blocks x L threads.
// ---------------------------------------------------------------------------
__global__ void prep_kernel(const float* __restrict__ lig_coord,
                            const float* __restrict__ pre_rot,
                            const float* __restrict__ trans,
                            float* __restrict__ new_lig) {
  int bt = blockIdx.x;          // b*T + t
  __shared__ float Qs[3][3];
  if (threadIdx.x == 0) {
    float a[3][3], q[3][3];
    #pragma unroll
    for (int i = 0; i < 3; ++i)
      #pragma unroll
      for (int j = 0; j < 3; ++j) {
        a[i][j] = pre_rot[(bt * 3 + i) * 3 + j];
        q[i][j] = (i == j) ? 1.f : 0.f;
      }
    // Householder QR, LAPACK slarfg sign convention: beta = -sign(alpha)*norm
    for (int k = 0; k < 3; ++k) {
      float alpha = a[k][k];
      float xn2 = 0.f;
      for (int i = k + 1; i < 3; ++i) xn2 += a[i][k] * a[i][k];
      float nrm = sqrtf(alpha * alpha + xn2);
      if (xn2 > 0.f && nrm > 0.f) {
        float beta = (alpha >= 0.f) ? -nrm : nrm;
        float tau = (beta - alpha) / beta;
        float inv = 1.f / (alpha - beta);
        float v[3] = {0.f, 0.f, 0.f};
        v[k] = 1.f;
        for (int i = k + 1; i < 3; ++i) v[i] = a[i][k] * inv;
        // a := (I - tau v v^T) a   (rows/cols k..2)
        for (int j = k; j < 3; ++j) {
          float w = 0.f;
          for (int i = k; i < 3; ++i) w += v[i] * a[i][j];
          w *= tau;
          for (int i = k; i < 3; ++i) a[i][j] -= w * v[i];
        }
        // q := q (I - tau v v^T)  -> final q = H0 H1 H2
        for (int i = 0; i < 3; ++i) {
          float w = 0.f;
          for (int j = k; j < 3; ++j) w += q[i][j] * v[j];
          w *= tau;
          for (int j = k; j < 3; ++j) q[i][j] -= w * v[j];
        }
      }
    }
    for (int i = 0; i < 3; ++i)
      for (int j = 0; j < 3; ++j) Qs[i][j] = q[i][j];
  }
  __syncthreads();
  int b = bt >> 4;              // T_ == 16
  int l = threadIdx.x;          // L_ == 128 threads
  float cx = lig_coord[(b * L_ + l) * 3 + 0];
  float cy = lig_coord[(b * L_ + l) * 3 + 1];
  float cz = lig_coord[(b * L_ + l) * 3 + 2];
  float tx = trans[bt * 3 + 0];
  float ty = trans[bt * 3 + 1];
  float tz = trans[bt * 3 + 2];
  float nx = Qs[0][0] * cx + Qs[0][1] * cy + Qs[0][2] * cz + tx;
  float ny = Qs[1][0] * cx + Qs[1][1] * cy + Qs[1][2] * cz + ty;
  float nz = Qs[2][0] * cx + Qs[2][1] * cy + Qs[2][2] * cz + tz;
  float* o = new_lig + ((size_t)bt * L_ + l) * 3;
  o[0] = nx; o[1] = ny; o[2] = nz;
}

// ---------------------------------------------------------------------------
// Kernel 2: atn[b,e,l,r] = sum_f lig_feat[b,l,e,f] * rec_feat[b,r,e,f]
// One block per (b, e, r-tile of 128). 128x128 C-tile, K=512 in BK=64 chunks.
// fp32 global -> convert to bf16 in staging -> LDS -> mfma_f32_16x16x32_bf16.
// Layouts (HW-verified, guide §3): A/B frag: idx=lane&15, k=(lane>>4)*8+j;
// C/D: col=lane&15, row=(lane>>4)*4+reg.
// ---------------------------------------------------------------------------
__launch_bounds__(256)
__global__ void gemm_kernel(const float* __restrict__ lig_feat,
                            const float* __restrict__ rec_feat,
                            float* __restrict__ atn) {
  const int rt = blockIdx.x;    // 0..7
  const int e  = blockIdx.y;    // 0..4
  const int b  = blockIdx.z;    // 0..7
  const int r0 = rt * 128;

  __shared__ short As[128 * 64];   // [l][k] bf16 bits, 16 KB
  __shared__ short Bs[128 * 64];   // [r][k] bf16 bits, 16 KB

  const int tid  = threadIdx.x;
  const int row  = tid >> 1;       // 0..127 (one LDS row per 2 threads)
  const int half = tid & 1;        // which 32-float half of the 64-wide chunk

  const float* aBase = lig_feat + ((size_t)(b * L_ + row) * E_ + e) * F_ + half * 32;
  const float* bBase = rec_feat + ((size_t)(b * R_ + r0 + row) * E_ + e) * F_ + half * 32;

  const int wave = tid >> 6;
  const int lane = tid & 63;
  const int wm = (wave >> 1) * 64;  // wave's C-row base
  const int wn = (wave & 1) * 64;   // wave's C-col base
  const int lrow = lane & 15;
  const int quad = lane >> 4;

  floatx4 acc[4][4];
  #pragma unroll
  for (int i = 0; i < 4; ++i)
    #pragma unroll
    for (int j = 0; j < 4; ++j)
      acc[i][j] = (floatx4){0.f, 0.f, 0.f, 0.f};

  for (int kc = 0; kc < 8; ++kc) {          // K chunks of 64
    floatx4 aR[8], bR[8];
    const floatx4* ap = (const floatx4*)(aBase + kc * 64);
    const floatx4* bp = (const floatx4*)(bBase + kc * 64);
    #pragma unroll
    for (int j = 0; j < 8; ++j) aR[j] = ap[j];
    #pragma unroll
    for (int j = 0; j < 8; ++j) bR[j] = bp[j];

    __syncthreads();   // previous chunk's LDS reads complete before overwrite
    short* aw = &As[row * 64 + half * 32];
    short* bw = &Bs[row * 64 + half * 32];
    #pragma unroll
    for (int j = 0; j < 4; ++j)
      *(short8*)(aw + j * 8) = pack8(aR[2 * j], aR[2 * j + 1]);
    #pragma unroll
    for (int j = 0; j < 4; ++j)
      *(short8*)(bw + j * 8) = pack8(bR[2 * j], bR[2 * j + 1]);
    __syncthreads();

    #pragma unroll
    for (int s = 0; s < 2; ++s) {           // two K=32 MFMA steps
      short8 af[4], bf[4];
      #pragma unroll
      for (int i = 0; i < 4; ++i)
        af[i] = *(const short8*)&As[(wm + i * 16 + lrow) * 64 + s * 32 + quad * 8];
      #pragma unroll
      for (int j = 0; j < 4; ++j)
        bf[j] = *(const short8*)&Bs[(wn + j * 16 + lrow) * 64 + s * 32 + quad * 8];
      #pragma unroll
      for (int i = 0; i < 4; ++i)
        #pragma unroll
        for (int j = 0; j < 4; ++j)
          acc[i][j] = __builtin_amdgcn_mfma_f32_16x16x32_bf16(af[i], bf[j], acc[i][j], 0, 0, 0);
    }
  }

  // store C tile: atn[((b*E+e)*L + m)*R + r0 + n]
  const size_t base = (size_t)(b * E_ + e) * L_ * R_;
  #pragma unroll
  for (int i = 0; i < 4; ++i)
    #pragma unroll
    for (int j = 0; j < 4; ++j)
      #pragma unroll
      for (int reg = 0; reg < 4; ++reg) {
        int m = wm + i * 16 + quad * 4 + reg;
        int n = wn + j * 16 + lrow;
        atn[base + (size_t)m * R_ + r0 + n] = acc[i][j][reg];
      }
}

// ---------------------------------------------------------------------------
// Kernel 3: U[b,t] += sum_{l,r,e} atn[b,e,l,r] * d(b,t,l,r)^exp[e]
// One block per (b,l); 256 threads stride over r. exps = [-3,-2,-1,1,2]:
// one rsqrt(d2) yields all five powers. Mask: skip l>=ligN, zero r>=recN.
// ---------------------------------------------------------------------------
__launch_bounds__(256)
__global__ void reduce_kernel(const float* __restrict__ atn,
                              const float* __restrict__ new_lig,
                              const float* __restrict__ rec_coord,
                              const int* __restrict__ lig_counts,
                              const int* __restrict__ rec_counts,
                              float* __restrict__ out) {
  const int b = blockIdx.x >> 7;
  const int l = blockIdx.x & 127;
  if (l >= lig_counts[b]) return;       // block-uniform exit
  const int recN = rec_counts[b];
  const int tid = threadIdx.x;

  __shared__ float nl[T_][3];
  if (tid < T_ * 3)
    nl[tid / 3][tid % 3] =
        new_lig[((size_t)(b * T_ + tid / 3) * L_ + l) * 3 + (tid % 3)];
  __syncthreads();

  float u[T_];
  #pragma unroll
  for (int t = 0; t < T_; ++t) u[t] = 0.f;

  const size_t plane = (size_t)L_ * R_;
  const size_t lr = (size_t)l * R_;

  for (int rr = 0; rr < R_ / 256; ++rr) {
    const int r = tid + rr * 256;
    const float msk = (r < recN) ? 1.f : 0.f;
    const size_t off = lr + r;
    const float a0 = atn[(size_t)(b * E_ + 0) * plane + off] * msk;  // d^-3
    const float a1 = atn[(size_t)(b * E_ + 1) * plane + off] * msk;  // d^-2
    const float a2 = atn[(size_t)(b * E_ + 2) * plane + off] * msk;  // d^-1
    const float a3 = atn[(size_t)(b * E_ + 3) * plane + off] * msk;  // d^1
    const float a4 = atn[(size_t)(b * E_ + 4) * plane + off] * msk;  // d^2
    const float rx = rec_coord[((size_t)b * R_ + r) * 3 + 0];
    const float ry = rec_coord[((size_t)b * R_ + r) * 3 + 1];
    const float rz = rec_coord[((size_t)b * R_ + r) * 3 + 2];
    #pragma unroll
    for (int t = 0; t < T_; ++t) {
      float dx = nl[t][0] - rx;
      float dy = nl[t][1] - ry;
      float dz = nl[t][2] - rz;
      float d2 = fmaf(dx, dx, fmaf(dy, dy, dz * dz));
      d2 = fmaxf(d2, 1e-20f);           // guard inf*0 on (prob-0) coincident pts
      float rs  = rsqrtf(d2);           // d^-1
      float rs2 = rs * rs;              // d^-2
      float rs3 = rs2 * rs;             // d^-3
      float d1  = d2 * rs;              // d^1
      float c = a0 * rs3;
      c = fmaf(a1, rs2, c);
      c = fmaf(a2, rs, c);
      c = fmaf(a3, d1, c);
      c = fmaf(a4, d2, c);
      u[t] += c;
    }
  }

  // wave reduce (64 lanes), one atomic per wave per t
  #pragma unroll
  for (int t = 0; t < T_; ++t) {
    float v = u[t];
    #pragma unroll
    for (int m = 32; m > 0; m >>= 1) v += __shfl_xor(v, m, 64);
    if ((tid & 63) == 0) atomicAdd(&out[b * T_ + t], v);
  }
}

// ---------------------------------------------------------------------------
extern "C" void kernel_launch(void* const* d_in, const int* in_sizes, int n_in,
                              void* d_out, int out_size, void* d_ws, size_t ws_size,
                              hipStream_t stream) {
  const float* lig_feat   = (const float*)d_in[0];
  const float* rec_feat   = (const float*)d_in[1];
  const float* lig_coord  = (const float*)d_in[2];
  const float* rec_coord  = (const float*)d_in[3];
  const float* pre_rot    = (const float*)d_in[4];
  const float* trans      = (const float*)d_in[5];
  const int*   lig_counts = (const int*)d_in[6];
  const int*   rec_counts = (const int*)d_in[7];
  float* out = (float*)d_out;

  // workspace: new_lig [B,T,L,3] fp32 (768 KB) then atn [B,E,L,R] fp32 (20 MB)
  float* new_lig = (float*)d_ws;
  float* atn     = (float*)d_ws + (size_t)B_ * T_ * L_ * 3;

  hipMemsetAsync(d_out, 0, (size_t)B_ * T_ * sizeof(float), stream);
  prep_kernel<<<dim3(B_ * T_), dim3(L_), 0, stream>>>(lig_coord, pre_rot, trans, new_lig);
  gemm_kernel<<<dim3(R_ / 128, E_, B_), dim3(256), 0, stream>>>(lig_feat, rec_feat, atn);
  reduce_kernel<<<dim3(B_ * L_), dim3(256), 0, stream>>>(atn, new_lig, rec_coord,
                                                         lig_counts, rec_counts, out);
}

// Round 2
// 186.149 us; speedup vs baseline: 1.9230x; 1.9230x over previous
//
#include <hip/hip_runtime.h>
#include <hip/hip_bf16.h>

// Problem constants (from reference): B,T,L,R,E,F
#define B_ 8
#define T_ 16
#define L_ 128
#define R_ 1024
#define E_ 5
#define F_ 512

typedef short short8 __attribute__((ext_vector_type(8)));
typedef float floatx4 __attribute__((ext_vector_type(4)));

// fp32 -> bf16 bits, round-half-up
__device__ __forceinline__ unsigned short f2bf(float f) {
  unsigned u = __float_as_uint(f);
  return (unsigned short)((u + 0x8000u) >> 16);
}

__device__ __forceinline__ short8 pack8(floatx4 lo, floatx4 hi) {
  short8 v;
  v[0] = (short)f2bf(lo[0]); v[1] = (short)f2bf(lo[1]);
  v[2] = (short)f2bf(lo[2]); v[3] = (short)f2bf(lo[3]);
  v[4] = (short)f2bf(hi[0]); v[5] = (short)f2bf(hi[1]);
  v[6] = (short)f2bf(hi[2]); v[7] = (short)f2bf(hi[3]);
  return v;
}

// ---------------------------------------------------------------------------
// Kernel 1: rot = QR(pre_rot).Q (LAPACK Householder convention), then
// new_lig[b,t,l,:] = rot[b,t] @ lig_coord[b,l] + trans[b,t].
// ---------------------------------------------------------------------------
__global__ void prep_kernel(const float* __restrict__ lig_coord,
                            const float* __restrict__ pre_rot,
                            const float* __restrict__ trans,
                            float* __restrict__ new_lig) {
  int bt = blockIdx.x;
  __shared__ float Qs[3][3];
  if (threadIdx.x == 0) {
    float a[3][3], q[3][3];
    #pragma unroll
    for (int i = 0; i < 3; ++i)
      #pragma unroll
      for (int j = 0; j < 3; ++j) {
        a[i][j] = pre_rot[(bt * 3 + i) * 3 + j];
        q[i][j] = (i == j) ? 1.f : 0.f;
      }
    for (int k = 0; k < 3; ++k) {
      float alpha = a[k][k];
      float xn2 = 0.f;
      for (int i = k + 1; i < 3; ++i) xn2 += a[i][k] * a[i][k];
      float nrm = sqrtf(alpha * alpha + xn2);
      if (xn2 > 0.f && nrm > 0.f) {
        float beta = (alpha >= 0.f) ? -nrm : nrm;
        float tau = (beta - alpha) / beta;
        float inv = 1.f / (alpha - beta);
        float v[3] = {0.f, 0.f, 0.f};
        v[k] = 1.f;
        for (int i = k + 1; i < 3; ++i) v[i] = a[i][k] * inv;
        for (int j = k; j < 3; ++j) {
          float w = 0.f;
          for (int i = k; i < 3; ++i) w += v[i] * a[i][j];
          w *= tau;
          for (int i = k; i < 3; ++i) a[i][j] -= w * v[i];
        }
        for (int i = 0; i < 3; ++i) {
          float w = 0.f;
          for (int j = k; j < 3; ++j) w += q[i][j] * v[j];
          w *= tau;
          for (int j = k; j < 3; ++j) q[i][j] -= w * v[j];
        }
      }
    }
    for (int i = 0; i < 3; ++i)
      for (int j = 0; j < 3; ++j) Qs[i][j] = q[i][j];
  }
  __syncthreads();
  int b = bt >> 4;
  int l = threadIdx.x;
  float cx = lig_coord[(b * L_ + l) * 3 + 0];
  float cy = lig_coord[(b * L_ + l) * 3 + 1];
  float cz = lig_coord[(b * L_ + l) * 3 + 2];
  float nx = Qs[0][0] * cx + Qs[0][1] * cy + Qs[0][2] * cz + trans[bt * 3 + 0];
  float ny = Qs[1][0] * cx + Qs[1][1] * cy + Qs[1][2] * cz + trans[bt * 3 + 1];
  float nz = Qs[2][0] * cx + Qs[2][1] * cy + Qs[2][2] * cz + trans[bt * 3 + 2];
  float* o = new_lig + ((size_t)bt * L_ + l) * 3;
  o[0] = nx; o[1] = ny; o[2] = nz;
}

// ---------------------------------------------------------------------------
// Kernel 2: atn[b,e,l,r] = sum_f lig_feat[b,l,e,f] * rec_feat[b,r,e,f]
// 128(M) x 64(N) C-tile per block -> 640 blocks (~2.5/CU). K=512 in BK=64.
// LDS 16B chunks XOR-swizzled by (row&7) to spread bank groups (unswizzled,
// all 16 lrow-lanes of a quad hit one 4-bank group on ds_read_b128).
// Early-exit for fully masked r-tiles (reduce multiplies them by 0 anyway).
// ---------------------------------------------------------------------------
__launch_bounds__(256)
__global__ void gemm_kernel(const float* __restrict__ lig_feat,
                            const float* __restrict__ rec_feat,
                            const int* __restrict__ rec_counts,
                            float* __restrict__ atn) {
  const int rt = blockIdx.x;    // 0..15
  const int e  = blockIdx.y;    // 0..4
  const int b  = blockIdx.z;    // 0..7
  const int r0 = rt * 64;
  if (r0 >= rec_counts[b]) return;   // tile fully masked downstream

  __shared__ short As[128 * 64];   // [l][k] bf16 bits, swizzled chunks, 16 KB
  __shared__ short Bs[64 * 64];    // [r][k] bf16 bits, swizzled chunks, 8 KB

  const int tid = threadIdx.x;
  // A staging: 2 threads per row, 32 floats each
  const int aRow  = tid >> 1;
  const int aHalf = tid & 1;
  const float* aBase = lig_feat + ((size_t)(b * L_ + aRow) * E_ + e) * F_ + aHalf * 32;
  // B staging: 4 threads per row, 16 floats each
  const int bRow = tid >> 2;
  const int bQ   = tid & 3;
  const float* bBase = rec_feat + ((size_t)(b * R_ + r0 + bRow) * E_ + e) * F_ + bQ * 16;

  const int wave = tid >> 6;
  const int lane = tid & 63;
  const int wm   = wave * 32;      // wave owns 32 C-rows x 64 C-cols
  const int lrow = lane & 15;
  const int quad = lane >> 4;

  floatx4 acc[2][4];
  #pragma unroll
  for (int i = 0; i < 2; ++i)
    #pragma unroll
    for (int j = 0; j < 4; ++j)
      acc[i][j] = (floatx4){0.f, 0.f, 0.f, 0.f};

  for (int kc = 0; kc < 8; ++kc) {
    floatx4 aR[8], bR[4];
    const floatx4* ap = (const floatx4*)(aBase + kc * 64);
    const floatx4* bp = (const floatx4*)(bBase + kc * 64);
    #pragma unroll
    for (int j = 0; j < 8; ++j) aR[j] = ap[j];
    #pragma unroll
    for (int j = 0; j < 4; ++j) bR[j] = bp[j];

    __syncthreads();
    // A: chunks c = aHalf*4 + j  (8-short = 16B chunks), swizzle c ^= row&7
    #pragma unroll
    for (int j = 0; j < 4; ++j) {
      int c = (aHalf * 4 + j) ^ (aRow & 7);
      *(short8*)&As[aRow * 64 + c * 8] = pack8(aR[2 * j], aR[2 * j + 1]);
    }
    // B: chunks c = bQ*2 + j
    #pragma unroll
    for (int j = 0; j < 2; ++j) {
      int c = (bQ * 2 + j) ^ (bRow & 7);
      *(short8*)&Bs[bRow * 64 + c * 8] = pack8(bR[2 * j], bR[2 * j + 1]);
    }
    __syncthreads();

    #pragma unroll
    for (int s = 0; s < 2; ++s) {
      short8 af[2], bf[4];
      #pragma unroll
      for (int i = 0; i < 2; ++i) {
        int row = wm + i * 16 + lrow;
        int c = (s * 4 + quad) ^ (row & 7);
        af[i] = *(const short8*)&As[row * 64 + c * 8];
      }
      #pragma unroll
      for (int j = 0; j < 4; ++j) {
        int row = j * 16 + lrow;
        int c = (s * 4 + quad) ^ (row & 7);
        bf[j] = *(const short8*)&Bs[row * 64 + c * 8];
      }
      #pragma unroll
      for (int i = 0; i < 2; ++i)
        #pragma unroll
        for (int j = 0; j < 4; ++j)
          acc[i][j] = __builtin_amdgcn_mfma_f32_16x16x32_bf16(af[i], bf[j], acc[i][j], 0, 0, 0);
    }
  }

  const size_t base = (size_t)(b * E_ + e) * L_ * R_;
  #pragma unroll
  for (int i = 0; i < 2; ++i)
    #pragma unroll
    for (int j = 0; j < 4; ++j)
      #pragma unroll
      for (int reg = 0; reg < 4; ++reg) {
        int m = wm + i * 16 + quad * 4 + reg;
        int n = j * 16 + lrow;
        atn[base + (size_t)m * R_ + r0 + n] = acc[i][j][reg];
      }
}

// ---------------------------------------------------------------------------
// Kernel 3: partial[b,t,l] = sum_{r,e} atn[b,e,l,r] * d(b,t,l,r)^exp[e]
// One block per (b,l); NO global atomics (they serialized 65k RMWs onto 4
// cache lines last round: 192us at 3% VALUBusy). Skips r-chunks >= recN.
// ---------------------------------------------------------------------------
__launch_bounds__(256)
__global__ void reduce_kernel(const float* __restrict__ atn,
                              const float* __restrict__ new_lig,
                              const float* __restrict__ rec_coord,
                              const int* __restrict__ lig_counts,
                              const int* __restrict__ rec_counts,
                              float* __restrict__ partial) {
  const int b = blockIdx.x >> 7;
  const int l = blockIdx.x & 127;
  const int tid = threadIdx.x;
  if (l >= lig_counts[b]) {             // write zeros so final_kernel is mask-free
    if (tid < T_) partial[(size_t)(b * T_ + tid) * L_ + l] = 0.f;
    return;
  }
  const int recN = rec_counts[b];
  const int rrEnd = (recN + 255) >> 8;

  __shared__ float nl[T_][3];
  __shared__ float sm[4][T_];
  if (tid < T_ * 3)
    nl[tid / 3][tid % 3] =
        new_lig[((size_t)(b * T_ + tid / 3) * L_ + l) * 3 + (tid % 3)];
  __syncthreads();

  float u[T_];
  #pragma unroll
  for (int t = 0; t < T_; ++t) u[t] = 0.f;

  const size_t plane = (size_t)L_ * R_;
  const size_t lr = (size_t)l * R_;

  for (int rr = 0; rr < rrEnd; ++rr) {
    const int r = tid + rr * 256;
    const float msk = (r < recN) ? 1.f : 0.f;
    const size_t off = lr + r;
    const float a0 = atn[(size_t)(b * E_ + 0) * plane + off] * msk;  // d^-3
    const float a1 = atn[(size_t)(b * E_ + 1) * plane + off] * msk;  // d^-2
    const float a2 = atn[(size_t)(b * E_ + 2) * plane + off] * msk;  // d^-1
    const float a3 = atn[(size_t)(b * E_ + 3) * plane + off] * msk;  // d^1
    const float a4 = atn[(size_t)(b * E_ + 4) * plane + off] * msk;  // d^2
    const float rx = rec_coord[((size_t)b * R_ + r) * 3 + 0];
    const float ry = rec_coord[((size_t)b * R_ + r) * 3 + 1];
    const float rz = rec_coord[((size_t)b * R_ + r) * 3 + 2];
    #pragma unroll
    for (int t = 0; t < T_; ++t) {
      float dx = nl[t][0] - rx;
      float dy = nl[t][1] - ry;
      float dz = nl[t][2] - rz;
      float d2 = fmaf(dx, dx, fmaf(dy, dy, dz * dz));
      d2 = fmaxf(d2, 1e-20f);
      float rs  = rsqrtf(d2);
      float rs2 = rs * rs;
      float rs3 = rs2 * rs;
      float d1  = d2 * rs;
      float c = a0 * rs3;
      c = fmaf(a1, rs2, c);
      c = fmaf(a2, rs, c);
      c = fmaf(a3, d1, c);
      c = fmaf(a4, d2, c);
      u[t] += c;
    }
  }

  const int wave = tid >> 6;
  #pragma unroll
  for (int t = 0; t < T_; ++t) {
    float v = u[t];
    #pragma unroll
    for (int m = 32; m > 0; m >>= 1) v += __shfl_xor(v, m, 64);
    if ((tid & 63) == 0) sm[wave][t] = v;
  }
  __syncthreads();
  if (tid < T_)
    partial[(size_t)(b * T_ + tid) * L_ + l] =
        sm[0][tid] + sm[1][tid] + sm[2][tid] + sm[3][tid];
}

// ---------------------------------------------------------------------------
// Kernel 4: out[b,t] = sum_l partial[b,t,l]   (128 blocks x 128 threads)
// ---------------------------------------------------------------------------
__global__ void final_kernel(const float* __restrict__ partial,
                             float* __restrict__ out) {
  const int bt = blockIdx.x;
  const int l = threadIdx.x;
  float v = partial[(size_t)bt * L_ + l];
  #pragma unroll
  for (int m = 32; m > 0; m >>= 1) v += __shfl_xor(v, m, 64);
  __shared__ float s[2];
  if ((l & 63) == 0) s[l >> 6] = v;
  __syncthreads();
  if (l == 0) out[bt] = s[0] + s[1];
}

// ---------------------------------------------------------------------------
extern "C" void kernel_launch(void* const* d_in, const int* in_sizes, int n_in,
                              void* d_out, int out_size, void* d_ws, size_t ws_size,
                              hipStream_t stream) {
  const float* lig_feat   = (const float*)d_in[0];
  const float* rec_feat   = (const float*)d_in[1];
  const float* lig_coord  = (const float*)d_in[2];
  const float* rec_coord  = (const float*)d_in[3];
  const float* pre_rot    = (const float*)d_in[4];
  const float* trans      = (const float*)d_in[5];
  const int*   lig_counts = (const int*)d_in[6];
  const int*   rec_counts = (const int*)d_in[7];
  float* out = (float*)d_out;

  // ws: new_lig [B,T,L,3] | atn [B,E,L,R] | partial [B,T,L]  (~21.3 MB fp32)
  float* new_lig = (float*)d_ws;
  float* atn     = new_lig + (size_t)B_ * T_ * L_ * 3;
  float* partial = atn + (size_t)B_ * E_ * L_ * R_;

  prep_kernel<<<dim3(B_ * T_), dim3(L_), 0, stream>>>(lig_coord, pre_rot, trans, new_lig);
  gemm_kernel<<<dim3(R_ / 64, E_, B_), dim3(256), 0, stream>>>(lig_feat, rec_feat,
                                                               rec_counts, atn);
  reduce_kernel<<<dim3(B_ * L_), dim3(256), 0, stream>>>(atn, new_lig, rec_coord,
                                                         lig_counts, rec_counts, partial);
  final_kernel<<<dim3(B_ * T_), dim3(128), 0, stream>>>(partial, out);
}